// Round 14
// baseline (1263.677 us; speedup 1.0000x reference)
//
#include <hip/hip_runtime.h>
#include <stdint.h>

// ---------------- threefry2x32 (bit-exact JAX) ----------------
__host__ __device__ static inline void threefry2x32(uint32_t k0, uint32_t k1,
                                                    uint32_t x0, uint32_t x1,
                                                    uint32_t* o0, uint32_t* o1) {
  uint32_t ks2 = k0 ^ k1 ^ 0x1BD11BDAu;
  x0 += k0; x1 += k1;
#define TF_RND(r) { x0 += x1; x1 = (x1 << (r)) | (x1 >> (32 - (r))); x1 ^= x0; }
  TF_RND(13) TF_RND(15) TF_RND(26) TF_RND(6)
  x0 += k1; x1 += ks2 + 1u;
  TF_RND(17) TF_RND(29) TF_RND(16) TF_RND(24)
  x0 += ks2; x1 += k0 + 2u;
  TF_RND(13) TF_RND(15) TF_RND(26) TF_RND(6)
  x0 += k0; x1 += k1 + 3u;
  TF_RND(17) TF_RND(29) TF_RND(16) TF_RND(24)
  x0 += k1; x1 += ks2 + 4u;
  TF_RND(13) TF_RND(15) TF_RND(26) TF_RND(6)
  x0 += ks2; x1 += k0 + 5u;
#undef TF_RND
  *o0 = x0; *o1 = x1;
}

// ---------------- edge-index dtype detect (int32 vs int64) ----------------
__global__ void k_detect(const int* __restrict__ ei, int twoE, int* __restrict__ flag) {
  int lane = threadIdx.x & 63;
  int v = (2 * lane + 1 < twoE) ? ei[2 * lane + 1] : 0;
  unsigned long long nz = __ballot(v != 0);
  if (lane == 0) flag[0] = (nz == 0ull) ? 1 : 0;  // 1 -> int64, 0 -> int32
}

__device__ static inline int load_idx(const void* p, long long i, int is64) {
  return is64 ? (int)((const long long*)p)[i] : ((const int*)p)[i];
}

// ---------------- degree histogram ----------------
__global__ void k_hist(const void* __restrict__ ei, int E, int* __restrict__ cnt,
                       const int* __restrict__ flag) {
  int is64 = flag[0];
  for (int e = blockIdx.x * blockDim.x + threadIdx.x; e < E; e += gridDim.x * blockDim.x) {
    int d = load_idx(ei, (long long)E + e, is64);
    atomicAdd(&cnt[d], 1);
  }
}

// ---------------- single-block exclusive scan + dis = rsqrt(deg+1) ----------------
__global__ __launch_bounds__(1024) void k_scan(const int* __restrict__ cnt,
                                               int* __restrict__ rp,
                                               float* __restrict__ dis, int n) {
  __shared__ int sd[1024];
  int tid = threadIdx.x;
  int chunk = (n + 1023) >> 10;
  int start = tid * chunk;
  int end = min(start + chunk, n);
  int s = 0;
  for (int i = start; i < end; ++i) s += cnt[i];
  sd[tid] = s;
  __syncthreads();
  for (int off = 1; off < 1024; off <<= 1) {
    int v = (tid >= off) ? sd[tid - off] : 0;
    __syncthreads();
    sd[tid] += v;
    __syncthreads();
  }
  int run = (tid == 0) ? 0 : sd[tid - 1];
  for (int i = start; i < end; ++i) {
    int c = cnt[i];
    rp[i] = run;
    dis[i] = rsqrtf((float)c + 1.0f);
    run += c;
  }
  if (tid == 1023) rp[n] = sd[1023];
}

// ---------------- CSR placement ----------------
__global__ void k_place(const void* __restrict__ ei, int E, const int* __restrict__ rp,
                        int* __restrict__ cursor, int* __restrict__ colA,
                        const int* __restrict__ flag) {
  int is64 = flag[0];
  for (int e = blockIdx.x * blockDim.x + threadIdx.x; e < E; e += gridDim.x * blockDim.x) {
    int s = load_idx(ei, e, is64);
    int d = load_idx(ei, (long long)E + e, is64);
    int pos = rp[d] + atomicAdd(&cursor[d], 1);
    colA[pos] = s;
  }
}

// ---------------- copy x into out[:, 0:64] ----------------
__global__ void k_copyx(const float4* __restrict__ x4, float4* __restrict__ out4, int n) {
  int total = n * 16;
  for (int i = blockIdx.x * blockDim.x + threadIdx.x; i < total; i += gridDim.x * blockDim.x) {
    int r = i >> 4, c = i & 15;
    out4[(size_t)r * 64 + c] = x4[i];
  }
}

// ---------------- GEMM: Yp = (H @ W) * dis[row] ----------------
__global__ __launch_bounds__(256) void k_gemm(const float* __restrict__ H,
                                              const float* __restrict__ W,
                                              const float* __restrict__ dis,
                                              float* __restrict__ Yp, int n) {
  __shared__ float Wl[64 * 64];
  int tid = threadIdx.x;
  {
    const float4* Wv = (const float4*)W;
    float4* Wlv = (float4*)Wl;
#pragma unroll
    for (int i = 0; i < 4; ++i) Wlv[tid + i * 256] = Wv[tid + i * 256];
  }
  __syncthreads();
  int row = blockIdx.x * 64 + (tid >> 2);
  if (row >= n) return;
  int tx = tid & 3;
  const float4* h4 = (const float4*)(H + (size_t)row * 64);
  float acc[16];
#pragma unroll
  for (int c = 0; c < 16; ++c) acc[c] = 0.0f;
#pragma unroll
  for (int k4 = 0; k4 < 16; ++k4) {
    float4 a = h4[k4];
    const float* w0 = &Wl[(k4 * 4 + 0) * 64 + tx * 16];
    const float* w1 = &Wl[(k4 * 4 + 1) * 64 + tx * 16];
    const float* w2 = &Wl[(k4 * 4 + 2) * 64 + tx * 16];
    const float* w3 = &Wl[(k4 * 4 + 3) * 64 + tx * 16];
#pragma unroll
    for (int c = 0; c < 16; ++c) {
      acc[c] = fmaf(a.x, w0[c], acc[c]);
      acc[c] = fmaf(a.y, w1[c], acc[c]);
      acc[c] = fmaf(a.z, w2[c], acc[c]);
      acc[c] = fmaf(a.w, w3[c], acc[c]);
    }
  }
  float dv = dis[row];
  float4* o = (float4*)(Yp + (size_t)row * 64 + tx * 16);
#pragma unroll
  for (int q = 0; q < 4; ++q) {
    float4 v;
    v.x = acc[q * 4 + 0] * dv;
    v.y = acc[q * 4 + 1] * dv;
    v.z = acc[q * 4 + 2] * dv;
    v.w = acc[q * 4 + 3] * dv;
    o[q] = v;
  }
}

// ---------------- aggregation (CSR gather) + bias + stats ----------------
// One wave per node; lane = feature. 8 independent accumulator streams keep
// 8 gather loads in flight to hide L2/L3 latency (avg degree ~16).
__global__ __launch_bounds__(256) void k_agg(const float* __restrict__ Yp,
                                             const int* __restrict__ rp,
                                             const int* __restrict__ colA,
                                             const float* __restrict__ dis,
                                             const float* __restrict__ bias,
                                             float* __restrict__ AGG,
                                             double* __restrict__ stats, int n) {
  __shared__ double red[512];
  int tid = threadIdx.x;
  int lane = tid & 63;
  int gw = (blockIdx.x * blockDim.x + tid) >> 6;
  int nw = (gridDim.x * blockDim.x) >> 6;
  double s0 = 0.0, s1 = 0.0;
  float b = bias[lane];
  for (int v = gw; v < n; v += nw) {
    float a0 = Yp[(size_t)v * 64 + lane];  // self loop (dis[v] applied at end)
    float a1 = 0.f, a2 = 0.f, a3 = 0.f, a4 = 0.f, a5 = 0.f, a6 = 0.f, a7 = 0.f;
    int beg = rp[v], end = rp[v + 1];
    for (int j0 = beg; j0 < end; j0 += 64) {
      int nn = min(64, end - j0);
      int c = (lane < nn) ? colA[j0 + lane] : 0;
      int t = 0;
      for (; t + 8 <= nn; t += 8) {
        int i0 = __shfl(c, t);
        int i1 = __shfl(c, t + 1);
        int i2 = __shfl(c, t + 2);
        int i3 = __shfl(c, t + 3);
        int i4 = __shfl(c, t + 4);
        int i5 = __shfl(c, t + 5);
        int i6 = __shfl(c, t + 6);
        int i7 = __shfl(c, t + 7);
        a0 += Yp[(size_t)i0 * 64 + lane];
        a1 += Yp[(size_t)i1 * 64 + lane];
        a2 += Yp[(size_t)i2 * 64 + lane];
        a3 += Yp[(size_t)i3 * 64 + lane];
        a4 += Yp[(size_t)i4 * 64 + lane];
        a5 += Yp[(size_t)i5 * 64 + lane];
        a6 += Yp[(size_t)i6 * 64 + lane];
        a7 += Yp[(size_t)i7 * 64 + lane];
      }
      for (; t + 4 <= nn; t += 4) {
        int i0 = __shfl(c, t);
        int i1 = __shfl(c, t + 1);
        int i2 = __shfl(c, t + 2);
        int i3 = __shfl(c, t + 3);
        a0 += Yp[(size_t)i0 * 64 + lane];
        a1 += Yp[(size_t)i1 * 64 + lane];
        a2 += Yp[(size_t)i2 * 64 + lane];
        a3 += Yp[(size_t)i3 * 64 + lane];
      }
      for (; t < nn; ++t) {
        int i0 = __shfl(c, t);
        a0 += Yp[(size_t)i0 * 64 + lane];
      }
    }
    float val = fmaf(dis[v], ((a0 + a1) + (a2 + a3)) + ((a4 + a5) + (a6 + a7)), b);
    AGG[(size_t)v * 64 + lane] = val;
    s0 += (double)val;
    s1 += (double)val * (double)val;
  }
  red[tid] = s0;
  red[256 + tid] = s1;
  __syncthreads();
  if (tid < 64) {
    double t0 = red[tid] + red[64 + tid] + red[128 + tid] + red[192 + tid];
    double t1 = red[256 + tid] + red[320 + tid] + red[384 + tid] + red[448 + tid];
    atomicAdd(&stats[tid], t0);
    atomicAdd(&stats[64 + tid], t1);
  }
}

// ---------------- BN + ReLU + dropout (threefry, partitionable mode) ----------------
// JAX >= 0.4.36: jax_threefry_partitionable defaults True. random_bits for
// element e = threefry(key, (hi(e), lo(e))) = threefry(key, (0, e)); 32-bit
// draw = out0 ^ out1. keep iff top bit clear (uniform(bits) < 0.5).
__global__ __launch_bounds__(256) void k_bn(const float* __restrict__ AGG,
                                            const double* __restrict__ stats,
                                            const float* __restrict__ g,
                                            const float* __restrict__ beta,
                                            float* __restrict__ dst, int ldo,
                                            uint32_t k0, uint32_t k1, int n,
                                            double invn) {
  __shared__ float ssc[64], ssh[64];
  if (threadIdx.x < 64) {
    int c = threadIdx.x;
    double mu = stats[c] * invn;
    double var = stats[64 + c] * invn - mu * mu;
    double scale = (double)g[c] / sqrt(var + 1e-5);
    ssc[c] = (float)scale;
    ssh[c] = (float)((double)beta[c] - mu * scale);
  }
  __syncthreads();
  int total = n * 64;
  for (int j = blockIdx.x * blockDim.x + threadIdx.x; j < total; j += gridDim.x * blockDim.x) {
    uint32_t b0, b1;
    threefry2x32(k0, k1, 0u, (uint32_t)j, &b0, &b1);
    uint32_t bits = b0 ^ b1;
    int col = j & 63;
    int row = j >> 6;
    float sc = ssc[col], sh = ssh[col];
    float v1 = AGG[j];
    float o1 = (bits & 0x80000000u) ? 0.0f : fmaxf(fmaf(sc, v1, sh), 0.0f) * 2.0f;
    dst[(size_t)row * ldo + col] = o1;
  }
}

extern "C" void kernel_launch(void* const* d_in, const int* in_sizes, int n_in,
                              void* d_out, int out_size, void* d_ws, size_t ws_size,
                              hipStream_t stream) {
  const float* x = (const float*)d_in[0];
  const void* ei = d_in[1];
  const float* Ws = (const float*)d_in[2];
  const float* bs = (const float*)d_in[3];
  const float* gs = (const float*)d_in[4];
  const float* betas = (const float*)d_in[5];
  float* out = (float*)d_out;

  int N = in_sizes[0] / 64;
  int E = in_sizes[1] / 2;

  // workspace carve-out (256B aligned)
  size_t off = 0;
  auto alloc = [&](size_t bytes) -> void* {
    void* p = (char*)d_ws + off;
    off += (bytes + 255) & ~(size_t)255;
    return p;
  };
  float* Yp   = (float*)alloc((size_t)N * 64 * 4);
  float* AGG  = (float*)alloc((size_t)N * 64 * 4);
  float* Hb   = (float*)alloc((size_t)N * 64 * 4);
  int* rp     = (int*)alloc(((size_t)N + 1) * 4);
  int* colA   = (int*)alloc((size_t)E * 4);
  int* cnt    = (int*)alloc((size_t)N * 4);
  int* cursor = (int*)alloc((size_t)N * 4);
  float* dis  = (float*)alloc((size_t)N * 4);
  double* stats = (double*)alloc(6 * 128 * 8);
  int* flag   = (int*)alloc(256);

  // dropout keys: jax.random.split(jax.random.key(42), 6) in PARTITIONABLE
  // mode: key_i = both outputs of threefry(key, (0, i)).
  uint32_t dk0[6], dk1[6];
  for (int i = 0; i < 6; ++i)
    threefry2x32(0u, 42u, 0u, (uint32_t)i, &dk0[i], &dk1[i]);

  hipMemsetAsync(cnt, 0, (size_t)N * 4, stream);
  hipMemsetAsync(cursor, 0, (size_t)N * 4, stream);
  hipMemsetAsync(stats, 0, 6 * 128 * 8, stream);

  k_detect<<<1, 64, 0, stream>>>((const int*)ei, 2 * E, flag);
  k_hist<<<2048, 256, 0, stream>>>(ei, E, cnt, flag);
  k_scan<<<1, 1024, 0, stream>>>(cnt, rp, dis, N);
  k_place<<<2048, 256, 0, stream>>>(ei, E, rp, cursor, colA, flag);
  k_copyx<<<2048, 256, 0, stream>>>((const float4*)x, (float4*)out, N);

  int gemm_blocks = (N + 63) / 64;
  int idx = 0;
  for (int bi = 0; bi < 3; ++bi) {
    const float* hin = x;
    for (int li = 0; li <= bi; ++li, ++idx) {
      k_gemm<<<gemm_blocks, 256, 0, stream>>>(hin, Ws + (size_t)idx * 4096, dis, Yp, N);
      k_agg<<<1024, 256, 0, stream>>>(Yp, rp, colA, dis, bs + idx * 64, AGG,
                                      stats + idx * 128, N);
      bool last = (li == bi);
      float* dst = last ? (out + 64 * (bi + 1)) : Hb;
      int ldo = last ? 256 : 64;
      k_bn<<<2048, 256, 0, stream>>>(AGG, stats + idx * 128, gs + idx * 64,
                                     betas + idx * 64, dst, ldo, dk0[idx], dk1[idx],
                                     N, 1.0 / (double)N);
      hin = Hb;
    }
  }
}

// Round 17
// 1130.695 us; speedup vs baseline: 1.1176x; 1.1176x over previous
//
#include <hip/hip_runtime.h>
#include <stdint.h>

// ---------------- threefry2x32 (bit-exact JAX) ----------------
__host__ __device__ static inline void threefry2x32(uint32_t k0, uint32_t k1,
                                                    uint32_t x0, uint32_t x1,
                                                    uint32_t* o0, uint32_t* o1) {
  uint32_t ks2 = k0 ^ k1 ^ 0x1BD11BDAu;
  x0 += k0; x1 += k1;
#define TF_RND(r) { x0 += x1; x1 = (x1 << (r)) | (x1 >> (32 - (r))); x1 ^= x0; }
  TF_RND(13) TF_RND(15) TF_RND(26) TF_RND(6)
  x0 += k1; x1 += ks2 + 1u;
  TF_RND(17) TF_RND(29) TF_RND(16) TF_RND(24)
  x0 += ks2; x1 += k0 + 2u;
  TF_RND(13) TF_RND(15) TF_RND(26) TF_RND(6)
  x0 += k0; x1 += k1 + 3u;
  TF_RND(17) TF_RND(29) TF_RND(16) TF_RND(24)
  x0 += k1; x1 += ks2 + 4u;
  TF_RND(13) TF_RND(15) TF_RND(26) TF_RND(6)
  x0 += ks2; x1 += k0 + 5u;
#undef TF_RND
  *o0 = x0; *o1 = x1;
}

// ---------------- edge-index dtype detect (int32 vs int64) ----------------
__global__ void k_detect(const int* __restrict__ ei, int twoE, int* __restrict__ flag) {
  int lane = threadIdx.x & 63;
  int v = (2 * lane + 1 < twoE) ? ei[2 * lane + 1] : 0;
  unsigned long long nz = __ballot(v != 0);
  if (lane == 0) flag[0] = (nz == 0ull) ? 1 : 0;  // 1 -> int64, 0 -> int32
}

__device__ static inline int load_idx(const void* p, long long i, int is64) {
  return is64 ? (int)((const long long*)p)[i] : ((const int*)p)[i];
}

// ---------------- degree histogram ----------------
__global__ void k_hist(const void* __restrict__ ei, int E, int* __restrict__ cnt,
                       const int* __restrict__ flag) {
  int is64 = flag[0];
  for (int e = blockIdx.x * blockDim.x + threadIdx.x; e < E; e += gridDim.x * blockDim.x) {
    int d = load_idx(ei, (long long)E + e, is64);
    atomicAdd(&cnt[d], 1);
  }
}

// ---------------- two-level scan: part sums -> scan partials -> write ----------------
// Replaces the single-block k_scan (227 us, 0.15% occupancy, uncoalesced
// stride-98 lane access). All three kernels are coalesced + multi-block.
__global__ __launch_bounds__(256) void k_part(const int* __restrict__ cnt,
                                              int* __restrict__ partial, int n) {
  __shared__ int red[256];
  int tid = threadIdx.x;
  int i = blockIdx.x * 256 + tid;
  red[tid] = (i < n) ? cnt[i] : 0;
  __syncthreads();
  for (int off = 128; off > 0; off >>= 1) {
    if (tid < off) red[tid] += red[tid + off];
    __syncthreads();
  }
  if (tid == 0) partial[blockIdx.x] = red[0];
}

__global__ __launch_bounds__(512) void k_scanp(const int* __restrict__ partial,
                                               int* __restrict__ poff,
                                               int* __restrict__ rp, int nblk, int n) {
  __shared__ int sd[512];
  int tid = threadIdx.x;
  sd[tid] = (tid < nblk) ? partial[tid] : 0;
  __syncthreads();
  for (int off = 1; off < 512; off <<= 1) {
    int v = (tid >= off) ? sd[tid - off] : 0;
    __syncthreads();
    sd[tid] += v;
    __syncthreads();
  }
  if (tid < nblk) poff[tid] = (tid == 0) ? 0 : sd[tid - 1];
  if (tid == 511) rp[n] = sd[511];
}

__global__ __launch_bounds__(256) void k_write(const int* __restrict__ cnt,
                                               const int* __restrict__ poff,
                                               int* __restrict__ rp,
                                               float* __restrict__ dis, int n) {
  __shared__ int sd[256];
  int tid = threadIdx.x;
  int i = blockIdx.x * 256 + tid;
  int c = (i < n) ? cnt[i] : 0;
  sd[tid] = c;
  __syncthreads();
  for (int off = 1; off < 256; off <<= 1) {
    int v = (tid >= off) ? sd[tid - off] : 0;
    __syncthreads();
    sd[tid] += v;
    __syncthreads();
  }
  if (i < n) {
    rp[i] = poff[blockIdx.x] + sd[tid] - c;  // exclusive prefix
    dis[i] = rsqrtf((float)c + 1.0f);
  }
}

// ---------------- CSR placement ----------------
__global__ void k_place(const void* __restrict__ ei, int E, const int* __restrict__ rp,
                        int* __restrict__ cursor, int* __restrict__ colA,
                        const int* __restrict__ flag) {
  int is64 = flag[0];
  for (int e = blockIdx.x * blockDim.x + threadIdx.x; e < E; e += gridDim.x * blockDim.x) {
    int s = load_idx(ei, e, is64);
    int d = load_idx(ei, (long long)E + e, is64);
    int pos = rp[d] + atomicAdd(&cursor[d], 1);
    colA[pos] = s;
  }
}

// ---------------- copy x into out[:, 0:64] ----------------
__global__ void k_copyx(const float4* __restrict__ x4, float4* __restrict__ out4, int n) {
  int total = n * 16;
  for (int i = blockIdx.x * blockDim.x + threadIdx.x; i < total; i += gridDim.x * blockDim.x) {
    int r = i >> 4, c = i & 15;
    out4[(size_t)r * 64 + c] = x4[i];
  }
}

// ---------------- GEMM: Yp = (H @ W) * dis[row] ----------------
__global__ __launch_bounds__(256) void k_gemm(const float* __restrict__ H,
                                              const float* __restrict__ W,
                                              const float* __restrict__ dis,
                                              float* __restrict__ Yp, int n) {
  __shared__ float Wl[64 * 64];
  int tid = threadIdx.x;
  {
    const float4* Wv = (const float4*)W;
    float4* Wlv = (float4*)Wl;
#pragma unroll
    for (int i = 0; i < 4; ++i) Wlv[tid + i * 256] = Wv[tid + i * 256];
  }
  __syncthreads();
  int row = blockIdx.x * 64 + (tid >> 2);
  if (row >= n) return;
  int tx = tid & 3;
  const float4* h4 = (const float4*)(H + (size_t)row * 64);
  float acc[16];
#pragma unroll
  for (int c = 0; c < 16; ++c) acc[c] = 0.0f;
#pragma unroll
  for (int k4 = 0; k4 < 16; ++k4) {
    float4 a = h4[k4];
    const float* w0 = &Wl[(k4 * 4 + 0) * 64 + tx * 16];
    const float* w1 = &Wl[(k4 * 4 + 1) * 64 + tx * 16];
    const float* w2 = &Wl[(k4 * 4 + 2) * 64 + tx * 16];
    const float* w3 = &Wl[(k4 * 4 + 3) * 64 + tx * 16];
#pragma unroll
    for (int c = 0; c < 16; ++c) {
      acc[c] = fmaf(a.x, w0[c], acc[c]);
      acc[c] = fmaf(a.y, w1[c], acc[c]);
      acc[c] = fmaf(a.z, w2[c], acc[c]);
      acc[c] = fmaf(a.w, w3[c], acc[c]);
    }
  }
  float dv = dis[row];
  float4* o = (float4*)(Yp + (size_t)row * 64 + tx * 16);
#pragma unroll
  for (int q = 0; q < 4; ++q) {
    float4 v;
    v.x = acc[q * 4 + 0] * dv;
    v.y = acc[q * 4 + 1] * dv;
    v.z = acc[q * 4 + 2] * dv;
    v.w = acc[q * 4 + 3] * dv;
    o[q] = v;
  }
}

// ---------------- aggregation (CSR gather) + bias + stats ----------------
// One wave per node; lane = feature. 8 independent accumulator streams keep
// 8 gather loads in flight; 2048 blocks -> 8192 waves (32/CU) for max TLP
// since the gather is L2/L3-latency-bound.
__global__ __launch_bounds__(256) void k_agg(const float* __restrict__ Yp,
                                             const int* __restrict__ rp,
                                             const int* __restrict__ colA,
                                             const float* __restrict__ dis,
                                             const float* __restrict__ bias,
                                             float* __restrict__ AGG,
                                             double* __restrict__ stats, int n) {
  __shared__ double red[512];
  int tid = threadIdx.x;
  int lane = tid & 63;
  int gw = (blockIdx.x * blockDim.x + tid) >> 6;
  int nw = (gridDim.x * blockDim.x) >> 6;
  double s0 = 0.0, s1 = 0.0;
  float b = bias[lane];
  for (int v = gw; v < n; v += nw) {
    float a0 = Yp[(size_t)v * 64 + lane];  // self loop (dis[v] applied at end)
    float a1 = 0.f, a2 = 0.f, a3 = 0.f, a4 = 0.f, a5 = 0.f, a6 = 0.f, a7 = 0.f;
    int beg = rp[v], end = rp[v + 1];
    for (int j0 = beg; j0 < end; j0 += 64) {
      int nn = min(64, end - j0);
      int c = (lane < nn) ? colA[j0 + lane] : 0;
      int t = 0;
      for (; t + 8 <= nn; t += 8) {
        int i0 = __shfl(c, t);
        int i1 = __shfl(c, t + 1);
        int i2 = __shfl(c, t + 2);
        int i3 = __shfl(c, t + 3);
        int i4 = __shfl(c, t + 4);
        int i5 = __shfl(c, t + 5);
        int i6 = __shfl(c, t + 6);
        int i7 = __shfl(c, t + 7);
        a0 += Yp[(size_t)i0 * 64 + lane];
        a1 += Yp[(size_t)i1 * 64 + lane];
        a2 += Yp[(size_t)i2 * 64 + lane];
        a3 += Yp[(size_t)i3 * 64 + lane];
        a4 += Yp[(size_t)i4 * 64 + lane];
        a5 += Yp[(size_t)i5 * 64 + lane];
        a6 += Yp[(size_t)i6 * 64 + lane];
        a7 += Yp[(size_t)i7 * 64 + lane];
      }
      for (; t + 4 <= nn; t += 4) {
        int i0 = __shfl(c, t);
        int i1 = __shfl(c, t + 1);
        int i2 = __shfl(c, t + 2);
        int i3 = __shfl(c, t + 3);
        a0 += Yp[(size_t)i0 * 64 + lane];
        a1 += Yp[(size_t)i1 * 64 + lane];
        a2 += Yp[(size_t)i2 * 64 + lane];
        a3 += Yp[(size_t)i3 * 64 + lane];
      }
      for (; t < nn; ++t) {
        int i0 = __shfl(c, t);
        a0 += Yp[(size_t)i0 * 64 + lane];
      }
    }
    float val = fmaf(dis[v], ((a0 + a1) + (a2 + a3)) + ((a4 + a5) + (a6 + a7)), b);
    AGG[(size_t)v * 64 + lane] = val;
    s0 += (double)val;
    s1 += (double)val * (double)val;
  }
  red[tid] = s0;
  red[256 + tid] = s1;
  __syncthreads();
  if (tid < 64) {
    double t0 = red[tid] + red[64 + tid] + red[128 + tid] + red[192 + tid];
    double t1 = red[256 + tid] + red[320 + tid] + red[384 + tid] + red[448 + tid];
    atomicAdd(&stats[tid], t0);
    atomicAdd(&stats[64 + tid], t1);
  }
}

// ---------------- BN + ReLU + dropout (threefry, partitionable mode) ----------------
// JAX >= 0.4.36: jax_threefry_partitionable defaults True. random_bits for
// element e = threefry(key, (hi(e), lo(e))) = threefry(key, (0, e)); 32-bit
// draw = out0 ^ out1. keep iff top bit clear (uniform(bits) < 0.5).
__global__ __launch_bounds__(256) void k_bn(const float* __restrict__ AGG,
                                            const double* __restrict__ stats,
                                            const float* __restrict__ g,
                                            const float* __restrict__ beta,
                                            float* __restrict__ dst, int ldo,
                                            uint32_t k0, uint32_t k1, int n,
                                            double invn) {
  __shared__ float ssc[64], ssh[64];
  if (threadIdx.x < 64) {
    int c = threadIdx.x;
    double mu = stats[c] * invn;
    double var = stats[64 + c] * invn - mu * mu;
    double scale = (double)g[c] / sqrt(var + 1e-5);
    ssc[c] = (float)scale;
    ssh[c] = (float)((double)beta[c] - mu * scale);
  }
  __syncthreads();
  int total = n * 64;
  for (int j = blockIdx.x * blockDim.x + threadIdx.x; j < total; j += gridDim.x * blockDim.x) {
    uint32_t b0, b1;
    threefry2x32(k0, k1, 0u, (uint32_t)j, &b0, &b1);
    uint32_t bits = b0 ^ b1;
    int col = j & 63;
    int row = j >> 6;
    float sc = ssc[col], sh = ssh[col];
    float v1 = AGG[j];
    float o1 = (bits & 0x80000000u) ? 0.0f : fmaxf(fmaf(sc, v1, sh), 0.0f) * 2.0f;
    dst[(size_t)row * ldo + col] = o1;
  }
}

extern "C" void kernel_launch(void* const* d_in, const int* in_sizes, int n_in,
                              void* d_out, int out_size, void* d_ws, size_t ws_size,
                              hipStream_t stream) {
  const float* x = (const float*)d_in[0];
  const void* ei = d_in[1];
  const float* Ws = (const float*)d_in[2];
  const float* bs = (const float*)d_in[3];
  const float* gs = (const float*)d_in[4];
  const float* betas = (const float*)d_in[5];
  float* out = (float*)d_out;

  int N = in_sizes[0] / 64;
  int E = in_sizes[1] / 2;
  int nblk = (N + 255) / 256;  // <= 512 required by k_scanp (N=100k -> 391)

  // workspace carve-out (256B aligned)
  size_t off = 0;
  auto alloc = [&](size_t bytes) -> void* {
    void* p = (char*)d_ws + off;
    off += (bytes + 255) & ~(size_t)255;
    return p;
  };
  float* Yp   = (float*)alloc((size_t)N * 64 * 4);
  float* AGG  = (float*)alloc((size_t)N * 64 * 4);
  float* Hb   = (float*)alloc((size_t)N * 64 * 4);
  int* rp     = (int*)alloc(((size_t)N + 1) * 4);
  int* colA   = (int*)alloc((size_t)E * 4);
  int* cnt    = (int*)alloc((size_t)N * 4);
  int* cursor = (int*)alloc((size_t)N * 4);
  float* dis  = (float*)alloc((size_t)N * 4);
  double* stats = (double*)alloc(6 * 128 * 8);
  int* partial = (int*)alloc((size_t)nblk * 4);
  int* poff    = (int*)alloc((size_t)nblk * 4);
  int* flag   = (int*)alloc(256);

  // dropout keys: jax.random.split(jax.random.key(42), 6) in PARTITIONABLE
  // mode: key_i = both outputs of threefry(key, (0, i)).
  uint32_t dk0[6], dk1[6];
  for (int i = 0; i < 6; ++i)
    threefry2x32(0u, 42u, 0u, (uint32_t)i, &dk0[i], &dk1[i]);

  hipMemsetAsync(cnt, 0, (size_t)N * 4, stream);
  hipMemsetAsync(cursor, 0, (size_t)N * 4, stream);
  hipMemsetAsync(stats, 0, 6 * 128 * 8, stream);

  k_detect<<<1, 64, 0, stream>>>((const int*)ei, 2 * E, flag);
  k_hist<<<2048, 256, 0, stream>>>(ei, E, cnt, flag);
  k_part<<<nblk, 256, 0, stream>>>(cnt, partial, N);
  k_scanp<<<1, 512, 0, stream>>>(partial, poff, rp, nblk, N);
  k_write<<<nblk, 256, 0, stream>>>(cnt, poff, rp, dis, N);
  k_place<<<2048, 256, 0, stream>>>(ei, E, rp, cursor, colA, flag);
  k_copyx<<<2048, 256, 0, stream>>>((const float4*)x, (float4*)out, N);

  int gemm_blocks = (N + 63) / 64;
  int idx = 0;
  for (int bi = 0; bi < 3; ++bi) {
    const float* hin = x;
    for (int li = 0; li <= bi; ++li, ++idx) {
      k_gemm<<<gemm_blocks, 256, 0, stream>>>(hin, Ws + (size_t)idx * 4096, dis, Yp, N);
      k_agg<<<2048, 256, 0, stream>>>(Yp, rp, colA, dis, bs + idx * 64, AGG,
                                      stats + idx * 128, N);
      bool last = (li == bi);
      float* dst = last ? (out + 64 * (bi + 1)) : Hb;
      int ldo = last ? 256 : 64;
      k_bn<<<2048, 256, 0, stream>>>(AGG, stats + idx * 128, gs + idx * 64,
                                     betas + idx * 64, dst, ldo, dk0[idx], dk1[idx],
                                     N, 1.0 / (double)N);
      hin = Hb;
    }
  }
}